// Round 2
// baseline (206.605 us; speedup 1.0000x reference)
//
#include <hip/hip_runtime.h>

// dcn_56925496541545: 3 iterations of (3x3 neighbor-avg stencil -> convex
// combo with (w1, 1-w1) -> sigmoid) on 4M flattened 3x3 patches; output is
// element 0 of each patch after iteration 3.
//
// Dependency-cone pruning: final out = x3[0] needs x2[{0,1,3,4}], which needs
// all 9 of x1 -> 14 sigmoids instead of 27.
//
// R7 (resubmitted; rounds 0-1 were infra failures, hypothesis unmeasured):
// same wave-local staging structure as R6 (best: 195.6 us), but input loads
// are PLAIN (cacheable) instead of nontemporal. Theory: 144 MB input fits in
// the 256 MB Infinity Cache; the bench replays the kernel, so steady-state
// reads can be served from L3 -- the nt flag on loads was explicitly telling
// the memory system to drop those lines. Output stores stay nontemporal
// (16 MB, written once, never re-read) to avoid evicting x.
// Predicted: TCC hit-rate up, FETCH_SIZE down, dur_us 195.6 -> 50-110 us.
// History: R3 (block staging + barrier) 197.2 us; R4 (half occ) 203.8;
// R5 (no LDS, 144B-stride loads) 244.3; R6 (wave-local LDS, nt loads) 195.6.
//
// Sigmoid: all inputs provably in [0,1] -> odd Taylor poly
// 1/2 + z/4 - z^3/48 + z^5/480, |err| <= 1.1e-4 (threshold 1.32e-2).

typedef float v4f __attribute__((ext_vector_type(4)));

__device__ __forceinline__ float sigmoid_poly(float z) {
    float z2 = z * z;
    float p = fmaf(z2, (1.0f / 480.0f), -(1.0f / 48.0f));
    p = fmaf(z2, p, 0.25f);
    return fmaf(z, p, 0.5f);
}

#define TPB 256
#define PPW 128              // patches per wave (128*9 = 1152 floats = 288 v4f)
#define WPB (TPB / 64)       // 4 waves per block
#define PPB (WPB * PPW)      // 512 patches per block
#define WV4 (PPW * 9 / 4)    // 288 float4 staged per wave

__device__ __forceinline__ float patch_chain(const float* __restrict__ a,
                                             float w1, float w2) {
    const float i3 = (1.0f / 3.0f), i5 = 0.2f, i8 = 0.125f;

    float b[9];
    b[0] = (a[1] + a[3] + a[4]) * i3;
    b[1] = (a[0] + a[2] + a[3] + a[4] + a[5]) * i5;
    b[2] = (a[1] + a[4] + a[5]) * i3;
    b[3] = (a[0] + a[1] + a[4] + a[6] + a[7]) * i5;
    b[4] = (a[0] + a[1] + a[2] + a[3] + a[5] + a[6] + a[7] + a[8]) * i8;
    b[5] = (a[1] + a[2] + a[4] + a[7] + a[8]) * i5;
    b[6] = (a[3] + a[4] + a[7]) * i3;
    b[7] = (a[3] + a[4] + a[5] + a[6] + a[8]) * i5;
    b[8] = (a[4] + a[5] + a[7]) * i3;

    float y[9];
#pragma unroll
    for (int k = 0; k < 9; ++k) y[k] = sigmoid_poly(fmaf(w1, a[k], w2 * b[k]));

    float c0 = (y[1] + y[3] + y[4]) * i3;
    float c1 = (y[0] + y[2] + y[3] + y[4] + y[5]) * i5;
    float c3 = (y[0] + y[1] + y[4] + y[6] + y[7]) * i5;
    float c4 = (y[0] + y[1] + y[2] + y[3] + y[5] + y[6] + y[7] + y[8]) * i8;

    float z0 = sigmoid_poly(fmaf(w1, y[0], w2 * c0));
    float z1 = sigmoid_poly(fmaf(w1, y[1], w2 * c1));
    float z3 = sigmoid_poly(fmaf(w1, y[3], w2 * c3));
    float z4 = sigmoid_poly(fmaf(w1, y[4], w2 * c4));

    float d0 = (z1 + z3 + z4) * i3;
    return sigmoid_poly(fmaf(w1, z0, w2 * d0));
}

__global__ __launch_bounds__(256) void dcn_56925496541545_kernel(
    const float* __restrict__ x, const float* __restrict__ w1p,
    float* __restrict__ out, int n)
{
    __shared__ float lds[PPB * 9];

    const int w    = threadIdx.x >> 6;
    const int lane = threadIdx.x & 63;
    const long waveBase = (long)blockIdx.x * PPB + (long)w * PPW;
    // n % PPW == 0 (4M % 128 == 0): waves are all-or-nothing. No barrier in
    // this kernel, so early return is legal.
    if (waveBase >= n) return;

    // Wave-local coalesced staging: 288 float4 (lanes 0-31 do 5, 32-63 do 4).
    // Plain loads (L2/L3-cacheable) -- x fits in Infinity Cache and the
    // bench replays; nt was forcing HBM re-fetch every iteration.
    const v4f* src4 = (const v4f*)(x + waveBase * 9);   // 144B-aligned
    float* ldsW = &lds[w * PPW * 9];
#pragma unroll
    for (int it = 0; it < 5; ++it) {
        const int i = lane + it * 64;
        if (i < WV4) {
            v4f v = src4[i];
            float* d = &ldsW[i << 2];                    // ds_write_b128
            d[0] = v.x; d[1] = v.y; d[2] = v.z; d[3] = v.w;
        }
    }
    // Same-wave DS ordering + compiler lgkmcnt waits make this correct with
    // no s_barrier; wave_barrier just pins the compile-time schedule.
    __builtin_amdgcn_wave_barrier();

    const float w1 = *w1p;
    const float w2 = 1.0f - w1;

    float a[9];
#pragma unroll
    for (int k = 0; k < 9; ++k) a[k] = ldsW[lane * 9 + k];        // stride 9
    float r0 = patch_chain(a, w1, w2);
#pragma unroll
    for (int k = 0; k < 9; ++k) a[k] = ldsW[(lane + 64) * 9 + k];
    float r1 = patch_chain(a, w1, w2);

    __builtin_nontemporal_store(r0, &out[waveBase + lane]);       // coalesced
    __builtin_nontemporal_store(r1, &out[waveBase + lane + 64]);
}

extern "C" void kernel_launch(void* const* d_in, const int* in_sizes, int n_in,
                              void* d_out, int out_size, void* d_ws, size_t ws_size,
                              hipStream_t stream) {
    const float* x   = (const float*)d_in[0];
    const float* w1p = (const float*)d_in[1];
    float* out = (float*)d_out;
    const int n = in_sizes[0] / 9;            // 4,000,000 patches (n%128==0)
    const int blocks = (n + PPB - 1) / PPB;   // 7813 (last block: 2 waves)
    dcn_56925496541545_kernel<<<blocks, TPB, 0, stream>>>(x, w1p, out, n);
}

// Round 3
// 195.352 us; speedup vs baseline: 1.0576x; 1.0576x over previous
//
#include <hip/hip_runtime.h>

// dcn_56925496541545: 3 iterations of (3x3 neighbor-avg stencil -> convex
// combo with (w1, 1-w1) -> sigmoid) on 4M flattened 3x3 patches; output is
// element 0 of each patch after iteration 3.
//
// Dependency-cone pruning: final out = x3[0] needs x2[{0,1,3,4}], which needs
// all 9 of x1 -> 14 sigmoids instead of 27.
//
// R8 = R6 restored (nt loads). R7 post-mortem: rocprof showed the timed
// region is dominated by TWO ~84us harness poison fills (576 MB @ 6.8 TB/s
// each); our kernel dispatch is <84us (absent from top-5). Implied kernel
// time: R6 ~28us vs 25.4us HBM floor (160MB @ 6.3TB/s). The 576MB of fill
// traffic between replays thrashes the 256MB L3, so there is NO steady-state
// L3 residency for x -- plain cacheable loads (R7) regressed 195.6->206.6 by
// competing for L3 lines with the fill stream. nt on both loads and stores
// is correct for this harness.
// History: R3 197.2; R4 203.8; R5 244.3; R6 195.6 (best); R7 206.6.
//
// Sigmoid: all inputs provably in [0,1] -> odd Taylor poly
// 1/2 + z/4 - z^3/48 + z^5/480, |err| <= 1.1e-4 (threshold 1.32e-2).

typedef float v4f __attribute__((ext_vector_type(4)));

__device__ __forceinline__ float sigmoid_poly(float z) {
    float z2 = z * z;
    float p = fmaf(z2, (1.0f / 480.0f), -(1.0f / 48.0f));
    p = fmaf(z2, p, 0.25f);
    return fmaf(z, p, 0.5f);
}

#define TPB 256
#define PPW 128              // patches per wave (128*9 = 1152 floats = 288 v4f)
#define WPB (TPB / 64)       // 4 waves per block
#define PPB (WPB * PPW)      // 512 patches per block
#define WV4 (PPW * 9 / 4)    // 288 float4 staged per wave

__device__ __forceinline__ float patch_chain(const float* __restrict__ a,
                                             float w1, float w2) {
    const float i3 = (1.0f / 3.0f), i5 = 0.2f, i8 = 0.125f;

    float b[9];
    b[0] = (a[1] + a[3] + a[4]) * i3;
    b[1] = (a[0] + a[2] + a[3] + a[4] + a[5]) * i5;
    b[2] = (a[1] + a[4] + a[5]) * i3;
    b[3] = (a[0] + a[1] + a[4] + a[6] + a[7]) * i5;
    b[4] = (a[0] + a[1] + a[2] + a[3] + a[5] + a[6] + a[7] + a[8]) * i8;
    b[5] = (a[1] + a[2] + a[4] + a[7] + a[8]) * i5;
    b[6] = (a[3] + a[4] + a[7]) * i3;
    b[7] = (a[3] + a[4] + a[5] + a[6] + a[8]) * i5;
    b[8] = (a[4] + a[5] + a[7]) * i3;

    float y[9];
#pragma unroll
    for (int k = 0; k < 9; ++k) y[k] = sigmoid_poly(fmaf(w1, a[k], w2 * b[k]));

    float c0 = (y[1] + y[3] + y[4]) * i3;
    float c1 = (y[0] + y[2] + y[3] + y[4] + y[5]) * i5;
    float c3 = (y[0] + y[1] + y[4] + y[6] + y[7]) * i5;
    float c4 = (y[0] + y[1] + y[2] + y[3] + y[5] + y[6] + y[7] + y[8]) * i8;

    float z0 = sigmoid_poly(fmaf(w1, y[0], w2 * c0));
    float z1 = sigmoid_poly(fmaf(w1, y[1], w2 * c1));
    float z3 = sigmoid_poly(fmaf(w1, y[3], w2 * c3));
    float z4 = sigmoid_poly(fmaf(w1, y[4], w2 * c4));

    float d0 = (z1 + z3 + z4) * i3;
    return sigmoid_poly(fmaf(w1, z0, w2 * d0));
}

__global__ __launch_bounds__(256) void dcn_56925496541545_kernel(
    const float* __restrict__ x, const float* __restrict__ w1p,
    float* __restrict__ out, int n)
{
    __shared__ float lds[PPB * 9];

    const int w    = threadIdx.x >> 6;
    const int lane = threadIdx.x & 63;
    const long waveBase = (long)blockIdx.x * PPB + (long)w * PPW;
    // n % PPW == 0 (4M % 128 == 0): waves are all-or-nothing. No barrier in
    // this kernel, so early return is legal.
    if (waveBase >= n) return;

    // Wave-local coalesced staging: 288 float4 (lanes 0-31 do 5, 32-63 do 4).
    // nt loads: L3 is thrashed by 576MB of harness fills between replays, so
    // there is nothing to cache; don't compete with the fill stream for lines.
    const v4f* src4 = (const v4f*)(x + waveBase * 9);   // 144B-aligned
    float* ldsW = &lds[w * PPW * 9];
#pragma unroll
    for (int it = 0; it < 5; ++it) {
        const int i = lane + it * 64;
        if (i < WV4) {
            v4f v = __builtin_nontemporal_load(&src4[i]);
            float* d = &ldsW[i << 2];                    // ds_write_b128
            d[0] = v.x; d[1] = v.y; d[2] = v.z; d[3] = v.w;
        }
    }
    // Same-wave DS ordering + compiler lgkmcnt waits make this correct with
    // no s_barrier; wave_barrier just pins the compile-time schedule.
    __builtin_amdgcn_wave_barrier();

    const float w1 = *w1p;
    const float w2 = 1.0f - w1;

    float a[9];
#pragma unroll
    for (int k = 0; k < 9; ++k) a[k] = ldsW[lane * 9 + k];        // stride 9
    float r0 = patch_chain(a, w1, w2);
#pragma unroll
    for (int k = 0; k < 9; ++k) a[k] = ldsW[(lane + 64) * 9 + k];
    float r1 = patch_chain(a, w1, w2);

    __builtin_nontemporal_store(r0, &out[waveBase + lane]);       // coalesced
    __builtin_nontemporal_store(r1, &out[waveBase + lane + 64]);
}

extern "C" void kernel_launch(void* const* d_in, const int* in_sizes, int n_in,
                              void* d_out, int out_size, void* d_ws, size_t ws_size,
                              hipStream_t stream) {
    const float* x   = (const float*)d_in[0];
    const float* w1p = (const float*)d_in[1];
    float* out = (float*)d_out;
    const int n = in_sizes[0] / 9;            // 4,000,000 patches (n%128==0)
    const int blocks = (n + PPB - 1) / PPB;   // 7813 (last block: 2 waves)
    dcn_56925496541545_kernel<<<blocks, TPB, 0, stream>>>(x, w1p, out, n);
}